// Round 7
// baseline (4283.254 us; speedup 1.0000x reference)
//
#include <hip/hip_runtime.h>
#include <math.h>

// Dims (fixed by the problem)
#define BB 8
#define SS 512
#define DD 512
#define HH 8
#define HSD 64
#define FFD 2048
#define LL 6
#define VV 1024
#define NROWS (BB*SS)          // 4096
#define EPS 1e-5f

// ---------------------------------------------------------------------------
// Embed (unchanged — passing config)
// ---------------------------------------------------------------------------
__global__ __launch_bounds__(256)
void embed_kernel(const float* __restrict__ tokens,
                  const float* __restrict__ emb,
                  float* __restrict__ x)
{
    const int n = blockIdx.x;            // 0..4095
    const int s = n & (SS - 1);
    const int t = threadIdx.x;
    __shared__ int sidx;
    #pragma unroll
    for (int r = 0; r < 4; ++r) {
        int v = t + 256 * r;
        if (tokens[(long)n * VV + v] > 0.5f) sidx = v;
    }
    __syncthreads();
    const int idx = sidx;
    const float sq = 22.62741699796952f; // sqrt(512)
    #pragma unroll
    for (int r = 0; r < 2; ++r) {
        int d = t + 256 * r;
        float e = emb[(long)idx * DD + d] * sq;
        float expo  = (2.0f * (float)d) / 512.0f;
        float denom = powf(10000.0f, expo);
        float val   = (float)s / denom;
        float pe = ((d & 1) == 0) ? sinf(val) : cosf(val);
        x[(long)n * DD + d] = e + pe;
    }
}

// ---------------------------------------------------------------------------
// Tiled GEMM: 128 x TNB tiles, BK=32, register-prefetch double buffering:
// next tile's global loads are issued BEFORE computing the current tile, so
// VMEM latency overlaps the FMA loop. Per-element accumulation stays ONE
// sequential-k fmac chain -> bitwise identical C (winner-selection-critical
// attention logits depend on upstream bits).
// QKVB: B is qkv_w [H][D][192]; global col c maps to head c/192, col c%192.
// ---------------------------------------------------------------------------
template<int TNB, bool BT, bool QKVB, bool BIAS, bool RELU, bool RES>
__global__ __launch_bounds__(256)
void gemm_t(const float* __restrict__ A, const float* __restrict__ B,
            const float* __restrict__ bias, const float* __restrict__ res,
            float* __restrict__ C,
            int M, int N, int K, int lda, int ldb, int ldc)
{
    constexpr int NW  = TNB / 16;          // cols per thread
    constexpr int PB  = TNB / 32;          // B staging regs (float4 each)
    constexpr int BSH = (TNB == 128) ? 5 : 4;
    const int t  = threadIdx.x;
    const int bm = blockIdx.y * 128;
    const int bn = blockIdx.x * TNB;
    __shared__ float As[32][132];
    __shared__ float Bs[32][TNB + 4];
    const int tx = t & 15;                 // col group (tx*NW)
    const int ty = t >> 4;                 // row group (ty*8)
    float acc[8][NW] = {};
    float4 aP[4], bP[PB];

    auto loadT = [&](int k0) {
        #pragma unroll
        for (int p = 0; p < 4; ++p) {      // A: 128x32
            int q = t + 256 * p;
            int r = q >> 3, kc = (q & 7) * 4;
            aP[p] = *(const float4*)(A + (long)(bm + r) * lda + k0 + kc);
        }
        if (QKVB) {
            #pragma unroll
            for (int p = 0; p < PB; ++p) { // B: per-head remap, row-major
                int q = t + 256 * p;
                int r = q >> BSH, c = (q & ((1 << BSH) - 1)) * 4;
                int col = bn + c;
                int h = (int)((unsigned)col / 192u);
                int j = col - h * 192;
                bP[p] = *(const float4*)(B + (long)h * (DD * 192) + (long)(k0 + r) * 192 + j);
            }
        } else if (!BT) {
            #pragma unroll
            for (int p = 0; p < PB; ++p) { // B: 32xTNB row-major
                int q = t + 256 * p;
                int r = q >> BSH, c = (q & ((1 << BSH) - 1)) * 4;
                bP[p] = *(const float4*)(B + (long)(k0 + r) * ldb + bn + c);
            }
        } else {
            #pragma unroll
            for (int p = 0; p < PB; ++p) { // B^T: TNB rows x 32 k
                int q = t + 256 * p;
                int r = q >> 3, kc = (q & 7) * 4;
                bP[p] = *(const float4*)(B + (long)(bn + r) * ldb + k0 + kc);
            }
        }
    };
    auto storeT = [&]() {
        #pragma unroll
        for (int p = 0; p < 4; ++p) {      // As[k][m] transposed
            int q = t + 256 * p;
            int r = q >> 3, kc = (q & 7) * 4;
            As[kc + 0][r] = aP[p].x; As[kc + 1][r] = aP[p].y;
            As[kc + 2][r] = aP[p].z; As[kc + 3][r] = aP[p].w;
        }
        if (QKVB || !BT) {
            #pragma unroll
            for (int p = 0; p < PB; ++p) {
                int q = t + 256 * p;
                int r = q >> BSH, c = (q & ((1 << BSH) - 1)) * 4;
                *(float4*)&Bs[r][c] = bP[p];
            }
        } else {
            #pragma unroll
            for (int p = 0; p < PB; ++p) { // Bs[k][n] transposed
                int q = t + 256 * p;
                int r = q >> 3, kc = (q & 7) * 4;
                Bs[kc + 0][r] = bP[p].x; Bs[kc + 1][r] = bP[p].y;
                Bs[kc + 2][r] = bP[p].z; Bs[kc + 3][r] = bP[p].w;
            }
        }
    };

    loadT(0);
    storeT();
    __syncthreads();

    for (int k0 = 0; k0 < K; k0 += 32) {
        const bool more = (k0 + 32) < K;
        if (more) loadT(k0 + 32);          // global loads in flight during FMA
        #pragma unroll
        for (int kk = 0; kk < 32; ++kk) {
            float a[8], bv[NW];
            *(float4*)&a[0] = *(const float4*)&As[kk][ty * 8];
            *(float4*)&a[4] = *(const float4*)&As[kk][ty * 8 + 4];
            #pragma unroll
            for (int g = 0; g < NW / 4; ++g)
                *(float4*)&bv[g * 4] = *(const float4*)&Bs[kk][tx * NW + g * 4];
            #pragma unroll
            for (int ii = 0; ii < 8; ++ii)
                #pragma unroll
                for (int jj = 0; jj < NW; ++jj)
                    acc[ii][jj] += a[ii] * bv[jj];
        }
        __syncthreads();
        if (more) {
            storeT();
            __syncthreads();
        }
    }

    #pragma unroll
    for (int ii = 0; ii < 8; ++ii) {
        int r = bm + ty * 8 + ii;
        #pragma unroll
        for (int jj = 0; jj < NW; ++jj) {
            int c = bn + tx * NW + jj;
            float v = acc[ii][jj];
            if (BIAS) v += bias[c];
            if (RELU) v = fmaxf(v, 0.0f);
            if (RES)  v += res[(long)r * ldc + c];
            C[(long)r * ldc + c] = v;
        }
    }
}

// ---------------------------------------------------------------------------
// Attention: exact softmax; FP expression trees byte-identical to the passing
// R1/R4/R5/R6 kernels. Execution changes only:
//  - register-prefetch of the next K / V tile's global loads before computing
//    the current tile (VMEM latency overlapped with dots / PV FMA).
//  - swizzled LDS layout + b128 reads as in R6.
// qkv layout: [n][h][192] (q:0..63,k:64..127,v:128..191), row stride 1536.
// ---------------------------------------------------------------------------
__device__ __forceinline__ int swz(int row, int col)
{   // swizzle on 4-dword groups; rows stay 16B-aligned
    return row * 64 + ((col & ~3) ^ ((row & 15) * 4)) + (col & 3);
}

__global__ __launch_bounds__(256)
void attn_kernel(const float* __restrict__ qkv, float* __restrict__ oc)
{
    const int i0 = blockIdx.x * 16;
    const int h  = blockIdx.y, b = blockIdx.z;
    const int t  = threadIdx.x;
    const int w  = t >> 6;               // wave 0..3 -> rows 4w..4w+3
    const int ln = t & 63;               // lane -> j offset / output d

    __shared__ float Qs[16][64];                   // Q rows (broadcast reads)
    __shared__ __align__(16) float KV[64 * 64];    // swizzled K / V^T tile
    __shared__ float Zb[16][512];                  // z, then P

    const long bhBase = (long)b * SS * 1536 + (long)h * 192;
    const int sr = t >> 4;               // staging row base
    const int sc = (t & 15) * 4;         // staging col base

    {   // stage Q: 16 rows x 64, one float4/thread
        *(float4*)&Qs[sr][sc] =
            *(const float4*)(qkv + bhBase + (long)(i0 + sr) * 1536 + sc);
    }

    float4 kp[4];
    auto loadK = [&](int kt) {
        const int j0 = kt * 64;
        #pragma unroll
        for (int p = 0; p < 4; ++p) {
            int q = t + 256 * p;
            int r = q >> 4, c = (q & 15) * 4;
            kp[p] = *(const float4*)(qkv + bhBase + (long)(j0 + r) * 1536 + 64 + c);
        }
    };
    auto storeK = [&]() {
        #pragma unroll
        for (int p = 0; p < 4; ++p) {
            int q = t + 256 * p;
            int r = q >> 4, c = (q & 15) * 4;
            *(float4*)&KV[swz(r, c)] = kp[p];
        }
    };

    // ---- pass 1: scores ----
    loadK(0);
    storeK();
    __syncthreads();

    for (int kt = 0; kt < 8; ++kt) {
        const int j0 = kt * 64;
        if (kt < 7) loadK(kt + 1);       // next K tile in flight

        float4 kreg[16];
        #pragma unroll
        for (int kk = 0; kk < 16; ++kk)
            kreg[kk] = *(const float4*)&KV[swz(ln, kk * 4)];

        #pragma unroll
        for (int c = 0; c < 4; ++c) {
            const int i = 4 * w + c;
            const float4* q4 = (const float4*)&Qs[i][0];
            float dot = 0.0f;
            #pragma unroll
            for (int kk = 0; kk < 16; ++kk) {
                float4 kv = kreg[kk];
                float4 qq = q4[kk];
                dot += qq.x * kv.x + qq.y * kv.y + qq.z * kv.z + qq.w * kv.w;
            }
            const int gi = i0 + i, gj = j0 + ln;
            Zb[i][j0 + ln] = (gj <= gi) ? 0.0f : (dot * -1.0e6f) * 0.125f;
        }
        __syncthreads();
        if (kt < 7) {
            storeK();
            __syncthreads();
        }
    }

    // ---- softmax (each wave: its 4 rows; verbatim reductions) ----
    #pragma unroll
    for (int c = 0; c < 4; ++c) {
        const int i = 4 * w + c;
        float p[8];
        float mx = -3.4e38f;
        #pragma unroll
        for (int r = 0; r < 8; ++r) { p[r] = Zb[i][r * 64 + ln]; mx = fmaxf(mx, p[r]); }
        #pragma unroll
        for (int o = 32; o >= 1; o >>= 1) mx = fmaxf(mx, __shfl_xor(mx, o));
        float sum = 0.0f;
        #pragma unroll
        for (int r = 0; r < 8; ++r) { p[r] = expf(p[r] - mx); sum += p[r]; }
        #pragma unroll
        for (int o = 32; o >= 1; o >>= 1) sum += __shfl_xor(sum, o);
        const float inv = 1.0f / sum;
        #pragma unroll
        for (int r = 0; r < 8; ++r) Zb[i][r * 64 + ln] = p[r] * inv;
    }
    __syncthreads();

    // ---- pass 2: O = P V, sequential-j fmac chain (verbatim statements) ----
    float4 vp[4];
    auto loadV = [&](int kt) {
        const int j0 = kt * 64;
        #pragma unroll
        for (int p = 0; p < 4; ++p) {
            int q = t + 256 * p;
            int r = q >> 4, c = (q & 15) * 4;
            vp[p] = *(const float4*)(qkv + bhBase + (long)(j0 + r) * 1536 + 128 + c);
        }
    };
    auto storeV = [&]() {                // V staged TRANSPOSED: KV[d][j]
        #pragma unroll
        for (int p = 0; p < 4; ++p) {
            int q = t + 256 * p;
            int r = q >> 4, c = (q & 15) * 4;
            KV[swz(c + 0, r)] = vp[p].x;
            KV[swz(c + 1, r)] = vp[p].y;
            KV[swz(c + 2, r)] = vp[p].z;
            KV[swz(c + 3, r)] = vp[p].w;
        }
    };

    float oA[4] = {0.0f, 0.0f, 0.0f, 0.0f};
    loadV(0);
    storeV();
    __syncthreads();

    for (int kt = 0; kt < 8; ++kt) {
        const int j0 = kt * 64;
        if (kt < 7) loadV(kt + 1);       // next V tile in flight

        float4 vreg[16];
        #pragma unroll
        for (int kk = 0; kk < 16; ++kk)
            vreg[kk] = *(const float4*)&KV[swz(ln, kk * 4)];

        #pragma unroll
        for (int c = 0; c < 4; ++c) {
            const int i = 4 * w + c;
            const float4* pr = (const float4*)&Zb[i][j0];
            float acc = oA[c];
            #pragma unroll
            for (int kk = 0; kk < 16; ++kk) {
                float4 pv = pr[kk];
                float4 vv = vreg[kk];
                acc += pv.x * vv.x;
                acc += pv.y * vv.y;
                acc += pv.z * vv.z;
                acc += pv.w * vv.w;
            }
            oA[c] = acc;
        }
        __syncthreads();
        if (kt < 7) {
            storeV();
            __syncthreads();
        }
    }

    // epilogue: concat-head layout oc[n][h*64 + d], d = lane (coalesced)
    #pragma unroll
    for (int c = 0; c < 4; ++c) {
        const int gi = i0 + 4 * w + c;
        oc[(long)(b * SS + gi) * DD + h * HSD + ln] = oA[c];
    }
}

// ---------------------------------------------------------------------------
// LayerNorm (unchanged)
// ---------------------------------------------------------------------------
__device__ __forceinline__ float blk_sum(float v, float* sb)
{
    #pragma unroll
    for (int m = 32; m >= 1; m >>= 1) v += __shfl_xor(v, m);
    if ((threadIdx.x & 63) == 0) sb[threadIdx.x >> 6] = v;
    __syncthreads();
    v = sb[0] + sb[1] + sb[2] + sb[3];
    __syncthreads();
    return v;
}

__global__ __launch_bounds__(256)
void ln_kernel(const float* __restrict__ in, const float* __restrict__ g,
               const float* __restrict__ bb, float* __restrict__ out)
{
    __shared__ float sb[4];
    const int n = blockIdx.x;
    const int t = threadIdx.x;
    const float* x = in + (long)n * DD;
    float v0 = x[t], v1 = x[t + 256];
    float total = blk_sum(v0 + v1, sb);
    float mean = total * (1.0f / 512.0f);
    float d0 = v0 - mean, d1 = v1 - mean;
    float ss = blk_sum(d0 * d0 + d1 * d1, sb);
    float var = ss * (1.0f / 512.0f);
    float inv = 1.0f / sqrtf(var + EPS);
    out[(long)n * DD + t]       = d0 * inv * g[t]       + bb[t];
    out[(long)n * DD + t + 256] = d1 * inv * g[t + 256] + bb[t + 256];
}

// ---------------------------------------------------------------------------
extern "C" void kernel_launch(void* const* d_in, const int* in_sizes, int n_in,
                              void* d_out, int out_size, void* d_ws, size_t ws_size,
                              hipStream_t stream)
{
    const float* tokens = (const float*)d_in[0];
    const float* emb    = (const float*)d_in[1];
    const float* qkv_w  = (const float*)d_in[2];
    const float* qkv_b  = (const float*)d_in[3];
    const float* out_w  = (const float*)d_in[4];
    const float* out_b  = (const float*)d_in[5];
    const float* w1     = (const float*)d_in[6];
    const float* b1     = (const float*)d_in[7];
    const float* w2     = (const float*)d_in[8];
    const float* b2     = (const float*)d_in[9];
    const float* ln1_g  = (const float*)d_in[10];
    const float* ln1_b  = (const float*)d_in[11];
    const float* ln2_g  = (const float*)d_in[12];
    const float* ln2_b  = (const float*)d_in[13];
    float* out = (float*)d_out;

    float* ws  = (float*)d_ws;
    float* x   = ws;                          // [4096,512]
    float* y   = x  + (long)NROWS * DD;       // [4096,512]
    float* oc  = y  + (long)NROWS * DD;       // [4096,512]
    float* big = oc + (long)NROWS * DD;       // [4096,2048]

    embed_kernel<<<NROWS, 256, 0, stream>>>(tokens, emb, x);

    for (int l = 0; l < LL; ++l) {
        const float* qw  = qkv_w + (long)l * HH * DD * 192;
        const float* qb  = qkv_b + (long)l * HH * 192;
        const float* ow  = out_w + (long)l * DD * DD;
        const float* ob  = out_b + (long)l * DD;
        const float* w1l = w1 + (long)l * DD * FFD;
        const float* b1l = b1 + (long)l * FFD;
        const float* w2l = w2 + (long)l * FFD * DD;
        const float* b2l = b2 + (long)l * DD;

        // QKV: [4096,512] @ per-head-remapped [512,1536] -> big (ldc=1536)
        gemm_t<64, false, true, true, false, false><<<dim3(24, 32), 256, 0, stream>>>(
            x, qw, qb, nullptr, big, NROWS, 1536, DD, DD, 192, 1536);

        attn_kernel<<<dim3(SS / 16, HH, BB), 256, 0, stream>>>(big, oc);

        // out-proj + bias + residual(x) -> y
        gemm_t<64, false, false, true, false, true><<<dim3(8, 32), 256, 0, stream>>>(
            oc, ow, ob, x, y, NROWS, DD, DD, DD, DD, DD);

        ln_kernel<<<NROWS, 256, 0, stream>>>(y, ln1_g + (long)l * DD, ln1_b + (long)l * DD, x);

        // FFN1 + relu -> big
        gemm_t<128, false, false, true, true, false><<<dim3(16, 32), 256, 0, stream>>>(
            x, w1l, b1l, nullptr, big, NROWS, FFD, DD, DD, FFD, FFD);

        // FFN2 + bias + residual(x) -> y
        gemm_t<64, false, false, true, false, true><<<dim3(8, 32), 256, 0, stream>>>(
            big, w2l, b2l, x, y, NROWS, DD, FFD, FFD, DD, DD);

        ln_kernel<<<NROWS, 256, 0, stream>>>(y, ln2_g + (long)l * DD, ln2_b + (long)l * DD, x);
    }

    // final: out = x @ emb^T
    gemm_t<64, true, false, false, false, false><<<dim3(16, 32), 256, 0, stream>>>(
        x, emb, nullptr, nullptr, out, NROWS, VV, DD, DD, DD, VV);
}